// Round 5
// baseline (22.237 us; speedup 1.0000x reference)
//
#include <hip/hip_runtime.h>
#include <math.h>

#define N        8192
#define NBLK     512            // 2 blocks/CU
#define THREADS  256
#define IPB      16             // i rows per block
#define R        8              // i rows per THREAD (register tile)
#define ITH      (IPB / R)      // 2 i-thread groups
#define SLICES   (THREADS / ITH)// 128 j-slices
#define G4       (N / 4)        // 2048 float4 groups over j
#define MITER    (G4 / SLICES)  // 16 main-loop iterations
#define MAGIC    0x5F3D59C1u    // != 0xAAAAAAAA poison, != 0

// Single standard dispatch. Block b computes complete risk_sum for
// i in [b*16, b*16+16) (8-row register tile), writes loss partial -> wsf[b],
// publishes flag[b]=MAGIC (device-scope). Block 0 CAS-consumes all 512 flags
// (MAGIC->0, self-cleaning for the next replay), then reduces -> out[0].
// No co-residency needed: only block 0 waits; everyone else runs to exit.
__global__ __launch_bounds__(THREADS, 2) void cox_all(
        const float* __restrict__ logRR,
        const float* __restrict__ ytime,
        const float* __restrict__ ystatus,
        float* __restrict__ wsf,
        unsigned int* __restrict__ flags,
        float* __restrict__ out) {
    __shared__ float s_yt[N];
    __shared__ float s_et[N];
    __shared__ float s_red[64];

    const int tid = threadIdx.x;
    const int b   = blockIdx.x;

    // Stage all 8192 j-values: ytime and exp(logRR), float4-vectorized.
    const float4* ytg = reinterpret_cast<const float4*>(ytime);
    const float4* thg = reinterpret_cast<const float4*>(logRR);
    float4* syt = reinterpret_cast<float4*>(s_yt);
    float4* set = reinterpret_cast<float4*>(s_et);
#pragma unroll
    for (int k = 0; k < G4 / THREADS; ++k) {   // 8 iters
        int idx = k * THREADS + tid;
        float4 y = ytg[idx];
        float4 t = thg[idx];
        syt[idx] = y;
        float4 e;
        e.x = __expf(t.x); e.y = __expf(t.y);
        e.z = __expf(t.z); e.w = __expf(t.w);
        set[idx] = e;
    }
    __syncthreads();

    const int it = tid & (ITH - 1);     // i-thread group 0..1
    const int sl = tid >> 1;            // j-slice 0..127

    float yti[R];
#pragma unroll
    for (int r = 0; r < R; ++r) yti[r] = ytime[b * IPB + it * R + r];

    float acc[R][2] = {};
#pragma unroll 4
    for (int m = 0; m < MITER; ++m) {   // 16 iters of 4 j's x 8 i's
        int jg = m * SLICES + sl;
        float4 yt = syt[jg];
        float4 et = set[jg];
#pragma unroll
        for (int r = 0; r < R; ++r) {
            float a0 = acc[r][0], a1 = acc[r][1];
            a0 += (yt.x >= yti[r]) ? et.x : 0.f;
            a1 += (yt.y >= yti[r]) ? et.y : 0.f;
            a0 += (yt.z >= yti[r]) ? et.z : 0.f;
            a1 += (yt.w >= yti[r]) ? et.w : 0.f;
            acc[r][0] = a0; acc[r][1] = a1;
        }
    }

    // Reduce over the 32 slices within each wave (lane^2.. keeps it-group).
    const int wave = tid >> 6;
    const int lane = tid & 63;
    float red[R];
#pragma unroll
    for (int r = 0; r < R; ++r) {
        float v = acc[r][0] + acc[r][1];
        v += __shfl_xor(v, 2);
        v += __shfl_xor(v, 4);
        v += __shfl_xor(v, 8);
        v += __shfl_xor(v, 16);
        v += __shfl_xor(v, 32);
        red[r] = v;
    }
    if (lane < ITH) {
#pragma unroll
        for (int r = 0; r < R; ++r)
            s_red[(wave * ITH + lane) * R + r] = red[r];
    }
    __syncthreads();

    // 16 lanes: combine 4 wave-partials per i, loss term, 16-lane reduce,
    // then publish the block partial (value release-fenced before flag).
    if (tid < IPB) {
        const int itl = tid >> 3;       // i_local = it*8 + r
        const int rl  = tid & 7;
        float risk = 0.f;
#pragma unroll
        for (int w = 0; w < THREADS / 64; ++w)
            risk += s_red[(w * ITH + itl) * R + rl];
        const int i = b * IPB + tid;
        float lv = (logRR[i] - __logf(risk)) * ystatus[i];
#pragma unroll
        for (int off = 8; off; off >>= 1) lv += __shfl_down(lv, off, 16);
        if (tid == 0) {
            wsf[b] = lv;
            __threadfence();                 // release wsf[b] to device scope
            atomicExch(&flags[b], MAGIC);    // publish (device-scope atomic)
        }
    }

    // Block 0: consume all flags (CAS MAGIC->0 resets them for next call),
    // then reduce the 512 partials in fixed order -> out[0].
    if (b == 0) {
        for (int k = tid; k < NBLK; k += THREADS) {
            while (atomicCAS(&flags[k], MAGIC, 0u) != MAGIC)
                __builtin_amdgcn_s_sleep(2);
        }
        __threadfence();                     // acquire before reading partials
        __syncthreads();
        float v = 0.f;
        for (int k = tid; k < NBLK; k += THREADS)   // ws[t] + ws[t+256]
            v += __hip_atomic_load(&wsf[k], __ATOMIC_RELAXED,
                                   __HIP_MEMORY_SCOPE_AGENT);
#pragma unroll
        for (int off = 32; off; off >>= 1) v += __shfl_down(v, off);
        if (lane == 0) s_red[wave] = v;
        __syncthreads();
        if (tid == 0)
            out[0] = -((s_red[0] + s_red[1]) + (s_red[2] + s_red[3]))
                     / (float)N;
    }
}

extern "C" void kernel_launch(void* const* d_in, const int* in_sizes, int n_in,
                              void* d_out, int out_size, void* d_ws, size_t ws_size,
                              hipStream_t stream) {
    const float* logRR   = (const float*)d_in[0];
    const float* ytime   = (const float*)d_in[1];
    const float* ystatus = (const float*)d_in[2];
    float* out = (float*)d_out;
    float* wsf = (float*)d_ws;
    unsigned int* flags = (unsigned int*)d_ws + NBLK;   // 2 KB + 2 KB scratch

    cox_all<<<NBLK, THREADS, 0, stream>>>(logRR, ytime, ystatus,
                                          wsf, flags, out);
}